// Round 1
// baseline (967.369 us; speedup 1.0000x reference)
//
#include <hip/hip_runtime.h>
#include <hip/hip_bf16.h>
#include <stdint.h>

typedef __bf16 bf16x8 __attribute__((ext_vector_type(8)));
typedef float  f32x4  __attribute__((ext_vector_type(4)));
typedef unsigned short u16;

__device__ __forceinline__ u16 f2bf(float f) {
    return __builtin_bit_cast(u16, __float2bfloat16(f));
}

__device__ __forceinline__ void gload16(const void* g, void* l) {
    __builtin_amdgcn_global_load_lds(
        (const __attribute__((address_space(1))) void*)g,
        (__attribute__((address_space(3))) void*)l,
        16, 0, 0);
}

// ---------------- quantization pipeline ----------------

__global__ void zero3_k(unsigned int* p) {
    if (threadIdx.x < 3) p[threadIdx.x] = 0u;
}

__global__ void maxabs_k(const float* __restrict__ w, int n, unsigned int* __restrict__ out) {
    const int tid = threadIdx.x;
    float m = 0.f;
    for (int i = blockIdx.x * blockDim.x + tid; i < n; i += gridDim.x * blockDim.x)
        m = fmaxf(m, fabsf(w[i]));
    #pragma unroll
    for (int off = 32; off > 0; off >>= 1)
        m = fmaxf(m, __shfl_down(m, off));
    __shared__ float red[4];
    if ((tid & 63) == 0) red[tid >> 6] = m;
    __syncthreads();
    if (tid == 0) {
        m = fmaxf(fmaxf(red[0], red[1]), fmaxf(red[2], red[3]));
        atomicMax(out, __float_as_uint(m));  // all values >=0: uint order == float order
    }
}

// w_q = clip(rint(w/scale), -n, n) * scale, scale = max|w|/n  (all fp32, matches jnp)
__global__ void quant_k(const float* __restrict__ w, int n,
                        const unsigned int* __restrict__ maxbits, float qn,
                        u16* __restrict__ out) {
    const float scale = __uint_as_float(*maxbits) / qn;
    for (int i = blockIdx.x * blockDim.x + threadIdx.x; i < n; i += gridDim.x * blockDim.x) {
        float q = rintf(w[i] / scale);          // RNE == jnp.round
        q = fminf(qn, fmaxf(-qn, q));
        out[i] = f2bf(q * scale);
    }
}

__global__ void cvt_k(const float* __restrict__ x, u16* __restrict__ o, long n) {
    const long stride = (long)gridDim.x * blockDim.x * 4;
    for (long i = ((long)blockIdx.x * blockDim.x + threadIdx.x) * 4; i < n; i += stride) {
        float4 v = *(const float4*)(x + i);
        unsigned int lo = (unsigned int)f2bf(v.x) | ((unsigned int)f2bf(v.y) << 16);
        unsigned int hi = (unsigned int)f2bf(v.z) | ((unsigned int)f2bf(v.w) << 16);
        *(uint2*)(o + i) = make_uint2(lo, hi);
    }
}

// ---------------- GEMM: C = A(MxK) * B(NxK)^T + bias, LeakyReLU ----------------
// m97 structure: 128x128 tile, BK=32, 4 waves (2x2), 4x4 16x16x32 frags per wave,
// global_load_lds width-16 staging, 2-barrier K-loop.

template<int BF16OUT>
__global__ __launch_bounds__(256, 2)
void gemm_bt(const u16* __restrict__ A, const u16* __restrict__ B,
             const float* __restrict__ bias, void* __restrict__ Cv,
             int M, int Nn, int K)
{
    __shared__ u16 lA[128 * 32];
    __shared__ u16 lB[128 * 32];

    const int tid  = threadIdx.x;
    const int lane = tid & 63;
    const int wave = tid >> 6;
    const int wm = wave >> 1, wn = wave & 1;
    const int bm = blockIdx.y * 128;
    const int bn = blockIdx.x * 128;

    // staging: thread t loads 16B at tile (row = t>>2, col = (t&3)*8); 2 issues each for A,B
    const int sr = tid >> 2;
    const int sc = (tid & 3) << 3;
    const u16* gA0 = A + (size_t)(bm + sr) * K + sc;
    const u16* gB0 = B + (size_t)(bn + sr) * K + sc;
    const size_t rowHalf = (size_t)64 * K;

    // LDS dest: wave-uniform base + lane*16B (linear [row][32] layout => byte = t*16)
    u16* lAw0 = lA + wave * 512;
    u16* lAw1 = lA + 2048 + wave * 512;
    u16* lBw0 = lB + wave * 512;
    u16* lBw1 = lB + 2048 + wave * 512;

    f32x4 acc[4][4] = {};

    const int fr = lane & 15;          // fragment row (A) / col-row (B)
    const int fk = (lane >> 4) << 3;   // k sub-offset: 8 contiguous bf16 per lane

    for (int k0 = 0; k0 < K; k0 += 32) {
        gload16(gA0 + k0,           lAw0);
        gload16(gA0 + rowHalf + k0, lAw1);
        gload16(gB0 + k0,           lBw0);
        gload16(gB0 + rowHalf + k0, lBw1);
        __syncthreads();   // compiler emits vmcnt(0) drain before barrier

        bf16x8 af[4], bfv[4];
        #pragma unroll
        for (int m = 0; m < 4; ++m)
            af[m] = *(const bf16x8*)&lA[(wm * 64 + m * 16 + fr) * 32 + fk];
        #pragma unroll
        for (int n = 0; n < 4; ++n)
            bfv[n] = *(const bf16x8*)&lB[(wn * 64 + n * 16 + fr) * 32 + fk];

        #pragma unroll
        for (int m = 0; m < 4; ++m)
            #pragma unroll
            for (int n = 0; n < 4; ++n)
                acc[m][n] = __builtin_amdgcn_mfma_f32_16x16x32_bf16(af[m], bfv[n], acc[m][n], 0, 0, 0);
        __syncthreads();
    }

    // C/D layout (m89-verified): col = lane&15, row = (lane>>4)*4 + j
    const int crow = (lane >> 4) << 2;
    const int ccol = lane & 15;
    #pragma unroll
    for (int n = 0; n < 4; ++n) {
        const int col = bn + wn * 64 + n * 16 + ccol;
        const float bv = bias[col];
        #pragma unroll
        for (int m = 0; m < 4; ++m) {
            const int row0 = bm + wm * 64 + m * 16 + crow;
            #pragma unroll
            for (int j = 0; j < 4; ++j) {
                float v = acc[m][n][j] + bv;
                v = (v >= 0.f) ? v : 0.01f * v;
                if (BF16OUT) {
                    ((u16*)Cv)[(size_t)(row0 + j) * Nn + col] = f2bf(v);
                } else {
                    ((float*)Cv)[(size_t)(row0 + j) * Nn + col] = v;
                }
            }
        }
    }
}

// ---------------- launch ----------------

extern "C" void kernel_launch(void* const* d_in, const int* in_sizes, int n_in,
                              void* d_out, int out_size, void* d_ws, size_t ws_size,
                              hipStream_t stream) {
    const float* x  = (const float*)d_in[0];
    const float* W0 = (const float*)d_in[1];
    const float* b0 = (const float*)d_in[2];
    const float* W1 = (const float*)d_in[3];
    const float* b1 = (const float*)d_in[4];
    const float* W2 = (const float*)d_in[5];
    const float* b2 = (const float*)d_in[6];

    const int N = 32768, D0 = 1024, D1 = 2048;

    char* ws = (char*)d_ws;
    u16* xbf = (u16*)ws;  ws += (size_t)N * D0 * 2;
    u16* h0  = (u16*)ws;  ws += (size_t)N * D1 * 2;
    u16* h1  = (u16*)ws;  ws += (size_t)N * D1 * 2;
    u16* w0q = (u16*)ws;  ws += (size_t)D1 * D0 * 2;
    u16* w1q = (u16*)ws;  ws += (size_t)D1 * D1 * 2;
    u16* w2q = (u16*)ws;  ws += (size_t)D1 * D1 * 2;
    unsigned int* scales = (unsigned int*)ws;

    zero3_k<<<1, 64, 0, stream>>>(scales);
    maxabs_k<<<256, 256, 0, stream>>>(W0, D1 * D0, scales + 0);
    maxabs_k<<<256, 256, 0, stream>>>(W1, D1 * D1, scales + 1);
    maxabs_k<<<256, 256, 0, stream>>>(W2, D1 * D1, scales + 2);
    quant_k<<<2048, 256, 0, stream>>>(W0, D1 * D0, scales + 0, 127.f, w0q);
    quant_k<<<2048, 256, 0, stream>>>(W1, D1 * D1, scales + 1, 7.f, w1q);
    quant_k<<<2048, 256, 0, stream>>>(W2, D1 * D1, scales + 2, 7.f, w2q);
    cvt_k<<<4096, 256, 0, stream>>>(x, xbf, (long)N * D0);

    dim3 grid(D1 / 128, N / 128);
    gemm_bt<1><<<grid, 256, 0, stream>>>(xbf, w0q, b0, h0, N, D1, D0);
    gemm_bt<1><<<grid, 256, 0, stream>>>(h0, w1q, b1, h1, N, D1, D1);
    gemm_bt<0><<<grid, 256, 0, stream>>>(h1, w2q, b2, d_out, N, D1, D1);
}

// Round 2
// 844.841 us; speedup vs baseline: 1.1450x; 1.1450x over previous
//
#include <hip/hip_runtime.h>
#include <hip/hip_bf16.h>
#include <stdint.h>

typedef __bf16 bf16x8 __attribute__((ext_vector_type(8)));
typedef float  f32x4  __attribute__((ext_vector_type(4)));
typedef unsigned short u16;

__device__ __forceinline__ u16 f2bf(float f) {
    return __builtin_bit_cast(u16, __float2bfloat16(f));
}

__device__ __forceinline__ void gload16(const void* g, void* l) {
    __builtin_amdgcn_global_load_lds(
        (const __attribute__((address_space(1))) void*)g,
        (__attribute__((address_space(3))) void*)l,
        16, 0, 0);
}

// ---------------- quantization pipeline ----------------

__global__ void zero3_k(unsigned int* p) {
    if (threadIdx.x < 3) p[threadIdx.x] = 0u;
}

__global__ void maxabs_k(const float* __restrict__ w, int n, unsigned int* __restrict__ out) {
    const int tid = threadIdx.x;
    float m = 0.f;
    for (int i = blockIdx.x * blockDim.x + tid; i < n; i += gridDim.x * blockDim.x)
        m = fmaxf(m, fabsf(w[i]));
    #pragma unroll
    for (int off = 32; off > 0; off >>= 1)
        m = fmaxf(m, __shfl_down(m, off));
    __shared__ float red[4];
    if ((tid & 63) == 0) red[tid >> 6] = m;
    __syncthreads();
    if (tid == 0) {
        m = fmaxf(fmaxf(red[0], red[1]), fmaxf(red[2], red[3]));
        atomicMax(out, __float_as_uint(m));  // all values >=0: uint order == float order
    }
}

// w_q = clip(rint(w/scale), -n, n) * scale, scale = max|w|/n  (all fp32, matches jnp)
__global__ void quant_k(const float* __restrict__ w, int n,
                        const unsigned int* __restrict__ maxbits, float qn,
                        u16* __restrict__ out) {
    const float scale = __uint_as_float(*maxbits) / qn;
    for (int i = blockIdx.x * blockDim.x + threadIdx.x; i < n; i += gridDim.x * blockDim.x) {
        float q = rintf(w[i] / scale);          // RNE == jnp.round
        q = fminf(qn, fmaxf(-qn, q));
        out[i] = f2bf(q * scale);
    }
}

__global__ void cvt_k(const float* __restrict__ x, u16* __restrict__ o, long n) {
    const long stride = (long)gridDim.x * blockDim.x * 4;
    for (long i = ((long)blockIdx.x * blockDim.x + threadIdx.x) * 4; i < n; i += stride) {
        float4 v = *(const float4*)(x + i);
        unsigned int lo = (unsigned int)f2bf(v.x) | ((unsigned int)f2bf(v.y) << 16);
        unsigned int hi = (unsigned int)f2bf(v.z) | ((unsigned int)f2bf(v.w) << 16);
        *(uint2*)(o + i) = make_uint2(lo, hi);
    }
}

// ---------------- GEMM: C = A(MxK) * B(NxK)^T + bias, LeakyReLU ----------------
// 256x256 tile, BK=32, 8 waves (2M x 4N), per-wave 128x64 = 8x4 16x16x32 frags.
// 4-deep LDS tile ring (4 x 32KB), one tile staged per loop iter (A half-pair
// early, B half-pair mid), counted vmcnt(10) steady state (3 tiles in flight),
// raw s_barrier (no drain), XOR swizzle slot^=row&3 on [row][4x16B] tiles,
// setprio(1) around MFMA clusters, XCD-aware block swizzle.

#define VM_TILE(kt, DO_STAGE, VMSTR)                                            \
  do {                                                                          \
    const int _buf = (kt) & 3;                                                  \
    const u16* _sA = &smem[_buf][0][0];                                         \
    const u16* _sB = &smem[_buf][1][0];                                         \
    if (DO_STAGE) {                                                             \
      const size_t _gk = (size_t)((kt) + 3) * 32;                               \
      const int _sb = ((kt) + 3) & 3;                                           \
      gload16(gA + _gk,              &smem[_sb][0][wave * 512]);                \
      gload16(gA + halfStride + _gk, &smem[_sb][0][4096 + wave * 512]);         \
    }                                                                           \
    asm volatile("s_waitcnt vmcnt(" VMSTR ")" ::: "memory");                    \
    __builtin_amdgcn_s_barrier();                                               \
    asm volatile("" ::: "memory");                                              \
    bf16x8 _bf[4], _af[4];                                                      \
    _Pragma("unroll") for (int n = 0; n < 4; ++n)                               \
        _bf[n] = *(const bf16x8*)(_sB + boff + n * 512);                        \
    _Pragma("unroll") for (int m = 0; m < 4; ++m)                               \
        _af[m] = *(const bf16x8*)(_sA + aoff + m * 512);                        \
    __builtin_amdgcn_s_setprio(1);                                              \
    _Pragma("unroll") for (int m = 0; m < 4; ++m)                               \
      _Pragma("unroll") for (int n = 0; n < 4; ++n)                             \
        acc[m][n] = __builtin_amdgcn_mfma_f32_16x16x32_bf16(_af[m], _bf[n],     \
                                                            acc[m][n], 0, 0, 0);\
    __builtin_amdgcn_s_setprio(0);                                              \
    if (DO_STAGE) {                                                             \
      const size_t _gk = (size_t)((kt) + 3) * 32;                               \
      const int _sb = ((kt) + 3) & 3;                                           \
      gload16(gB + _gk,              &smem[_sb][1][wave * 512]);                \
      gload16(gB + halfStride + _gk, &smem[_sb][1][4096 + wave * 512]);         \
    }                                                                           \
    _Pragma("unroll") for (int m = 0; m < 4; ++m)                               \
        _af[m] = *(const bf16x8*)(_sA + aoff + 2048 + m * 512);                 \
    __builtin_amdgcn_s_setprio(1);                                              \
    _Pragma("unroll") for (int m = 0; m < 4; ++m)                               \
      _Pragma("unroll") for (int n = 0; n < 4; ++n)                             \
        acc[4 + m][n] = __builtin_amdgcn_mfma_f32_16x16x32_bf16(_af[m], _bf[n], \
                                                     acc[4 + m][n], 0, 0, 0);   \
    __builtin_amdgcn_s_setprio(0);                                              \
    asm volatile("" ::: "memory");                                              \
    __builtin_amdgcn_s_barrier();                                               \
    asm volatile("" ::: "memory");                                              \
  } while (0)

template<int BF16OUT>
__global__ __launch_bounds__(512, 2)
void gemm8p(const u16* __restrict__ A, const u16* __restrict__ B,
            const float* __restrict__ bias, void* __restrict__ Cv,
            int M, int Nn, int K)
{
    __shared__ __align__(128) u16 smem[4][2][8192];  // [ring buf][A|B][256 rows x 32 cols]

    const int tid  = threadIdx.x;
    const int lane = tid & 63;
    const int wave = tid >> 6;
    const int wm = wave >> 2;   // 0..1 -> row offset wm*128
    const int wn = wave & 3;    // 0..3 -> col offset wn*64

    // XCD-aware bijective swizzle (gridDim.x % 8 == 0 here)
    const int nbx = Nn >> 8;
    const int cpx = gridDim.x >> 3;
    const int bid = blockIdx.x;
    const int swz = (bid & 7) * cpx + (bid >> 3);
    const int bn = (swz % nbx) << 8;
    const int bm = (swz / nbx) << 8;

    // staging: thread t -> LDS row t/4 (of a 128-row half), 16B slot t%4;
    // source column pre-swizzled: slot_src = (t%4) ^ (row&3)   (rule 21)
    const int srow = tid >> 2;
    const int scol = (((tid & 3) ^ (srow & 3)) << 3);
    const u16* gA = A + (size_t)(bm + srow) * K + scol;
    const u16* gB = B + (size_t)(bn + srow) * K + scol;
    const size_t halfStride = (size_t)128 * K;

    // frag ds_read offsets (elems): row*32 + (slot ^ (row&3))*8
    const int fr = lane & 15;
    const int slotp = (((lane >> 4) ^ (lane & 3)) << 3);
    const int aoff = (wm * 128 + fr) * 32 + slotp;   // + m*512 per m-frag
    const int boff = (wn * 64  + fr) * 32 + slotp;   // + n*512 per n-frag

    f32x4 acc[8][4] = {};

    // prologue: stage tiles 0..2 (12 loads/thread outstanding)
    #pragma unroll
    for (int t = 0; t < 3; ++t) {
        const size_t gk = (size_t)t * 32;
        gload16(gA + gk,              &smem[t][0][wave * 512]);
        gload16(gA + halfStride + gk, &smem[t][0][4096 + wave * 512]);
        gload16(gB + gk,              &smem[t][1][wave * 512]);
        gload16(gB + halfStride + gk, &smem[t][1][4096 + wave * 512]);
    }

    const int NT = K >> 5;
    for (int k = 0; k <= NT - 4; ++k)
        VM_TILE(k, true, "10");
    VM_TILE(NT - 3, false, "8");
    VM_TILE(NT - 2, false, "4");
    VM_TILE(NT - 1, false, "0");

    // C/D layout: col = lane&15, row = (lane>>4)*4 + j
    const int crow = (lane >> 4) << 2;
    const int ccol = lane & 15;
    #pragma unroll
    for (int n = 0; n < 4; ++n) {
        const int col = bn + wn * 64 + n * 16 + ccol;
        const float bv = bias[col];
        #pragma unroll
        for (int m = 0; m < 8; ++m) {
            const int row0 = bm + wm * 128 + m * 16 + crow;
            #pragma unroll
            for (int j = 0; j < 4; ++j) {
                float v = acc[m][n][j] + bv;
                v = (v >= 0.f) ? v : 0.01f * v;
                if (BF16OUT) {
                    ((u16*)Cv)[(size_t)(row0 + j) * Nn + col] = f2bf(v);
                } else {
                    ((float*)Cv)[(size_t)(row0 + j) * Nn + col] = v;
                }
            }
        }
    }
}

// ---------------- launch ----------------

extern "C" void kernel_launch(void* const* d_in, const int* in_sizes, int n_in,
                              void* d_out, int out_size, void* d_ws, size_t ws_size,
                              hipStream_t stream) {
    const float* x  = (const float*)d_in[0];
    const float* W0 = (const float*)d_in[1];
    const float* b0 = (const float*)d_in[2];
    const float* W1 = (const float*)d_in[3];
    const float* b1 = (const float*)d_in[4];
    const float* W2 = (const float*)d_in[5];
    const float* b2 = (const float*)d_in[6];

    const int N = 32768, D0 = 1024, D1 = 2048;

    char* ws = (char*)d_ws;
    u16* xbf = (u16*)ws;  ws += (size_t)N * D0 * 2;
    u16* h0  = (u16*)ws;  ws += (size_t)N * D1 * 2;
    u16* h1  = (u16*)ws;  ws += (size_t)N * D1 * 2;
    u16* w0q = (u16*)ws;  ws += (size_t)D1 * D0 * 2;
    u16* w1q = (u16*)ws;  ws += (size_t)D1 * D1 * 2;
    u16* w2q = (u16*)ws;  ws += (size_t)D1 * D1 * 2;
    unsigned int* scales = (unsigned int*)ws;

    zero3_k<<<1, 64, 0, stream>>>(scales);
    maxabs_k<<<256, 256, 0, stream>>>(W0, D1 * D0, scales + 0);
    maxabs_k<<<256, 256, 0, stream>>>(W1, D1 * D1, scales + 1);
    maxabs_k<<<256, 256, 0, stream>>>(W2, D1 * D1, scales + 2);
    quant_k<<<2048, 256, 0, stream>>>(W0, D1 * D0, scales + 0, 127.f, w0q);
    quant_k<<<2048, 256, 0, stream>>>(W1, D1 * D1, scales + 1, 7.f, w1q);
    quant_k<<<2048, 256, 0, stream>>>(W2, D1 * D1, scales + 2, 7.f, w2q);
    cvt_k<<<4096, 256, 0, stream>>>(x, xbf, (long)N * D0);

    const int blocks = (D1 / 256) * (N / 256);   // 8 * 128 = 1024, %8 == 0
    gemm8p<1><<<blocks, 512, 0, stream>>>(xbf, w0q, b0, h0, N, D1, D0);
    gemm8p<1><<<blocks, 512, 0, stream>>>(h0, w1q, b1, h1, N, D1, D1);
    gemm8p<0><<<blocks, 512, 0, stream>>>(h1, w2q, b2, d_out, N, D1, D1);
}

// Round 3
// 826.537 us; speedup vs baseline: 1.1704x; 1.0221x over previous
//
#include <hip/hip_runtime.h>
#include <hip/hip_bf16.h>
#include <stdint.h>

typedef __bf16 bf16x8 __attribute__((ext_vector_type(8)));
typedef float  f32x4  __attribute__((ext_vector_type(4)));
typedef unsigned short u16;

__device__ __forceinline__ u16 f2bf(float f) {
    return __builtin_bit_cast(u16, __float2bfloat16(f));
}

__device__ __forceinline__ void gload16(const void* g, void* l) {
    __builtin_amdgcn_global_load_lds(
        (const __attribute__((address_space(1))) void*)g,
        (__attribute__((address_space(3))) void*)l,
        16, 0, 0);
}

// ---------------- quantization pipeline ----------------

__global__ void zero3_k(unsigned int* p) {
    if (threadIdx.x < 3) p[threadIdx.x] = 0u;
}

__global__ void maxabs_k(const float* __restrict__ w, int n, unsigned int* __restrict__ out) {
    const int tid = threadIdx.x;
    float m = 0.f;
    for (int i = blockIdx.x * blockDim.x + tid; i < n; i += gridDim.x * blockDim.x)
        m = fmaxf(m, fabsf(w[i]));
    #pragma unroll
    for (int off = 32; off > 0; off >>= 1)
        m = fmaxf(m, __shfl_down(m, off));
    __shared__ float red[4];
    if ((tid & 63) == 0) red[tid >> 6] = m;
    __syncthreads();
    if (tid == 0) {
        m = fmaxf(fmaxf(red[0], red[1]), fmaxf(red[2], red[3]));
        atomicMax(out, __float_as_uint(m));  // all values >=0: uint order == float order
    }
}

// w_q = clip(rint(w/scale), -n, n) * scale, scale = max|w|/n  (all fp32, matches jnp)
__global__ void quant_k(const float* __restrict__ w, int n,
                        const unsigned int* __restrict__ maxbits, float qn,
                        u16* __restrict__ out) {
    const float scale = __uint_as_float(*maxbits) / qn;
    for (int i = blockIdx.x * blockDim.x + threadIdx.x; i < n; i += gridDim.x * blockDim.x) {
        float q = rintf(w[i] / scale);          // RNE == jnp.round
        q = fminf(qn, fmaxf(-qn, q));
        out[i] = f2bf(q * scale);
    }
}

__global__ void cvt_k(const float* __restrict__ x, u16* __restrict__ o, long n) {
    const long stride = (long)gridDim.x * blockDim.x * 4;
    for (long i = ((long)blockIdx.x * blockDim.x + threadIdx.x) * 4; i < n; i += stride) {
        float4 v = *(const float4*)(x + i);
        unsigned int lo = (unsigned int)f2bf(v.x) | ((unsigned int)f2bf(v.y) << 16);
        unsigned int hi = (unsigned int)f2bf(v.z) | ((unsigned int)f2bf(v.w) << 16);
        *(uint2*)(o + i) = make_uint2(lo, hi);
    }
}

// ---------------- GEMM: C = A(MxK) * B(NxK)^T + bias, LeakyReLU ----------------
// 256x256 tile, BK=32, 8 waves (2M x 4N), per-wave 128x64 = 8x4 16x16x32 frags.
// 4-deep LDS tile ring (4 x 32KB), counted vmcnt(10) (3 tiles in flight), raw
// s_barrier, XOR swizzle slot^=(row>>1)&3 (granule pos = 4*row+slot mod 8:
// only row bit0 survives 4*row, so slot must carry row bits 1-2 -> rows 0..7
// cover all 8 granule positions; 2-way residual = free), setprio around MFMA,
// XCD-bijective block swizzle, LDS-transpose coalesced epilogue.

#define VM_TILE(kt, DO_STAGE, VMSTR)                                            \
  do {                                                                          \
    const int _buf = (kt) & 3;                                                  \
    const u16* _sA = &smem[_buf][0][0];                                         \
    const u16* _sB = &smem[_buf][1][0];                                         \
    if (DO_STAGE) {                                                             \
      const size_t _gk = (size_t)((kt) + 3) * 32;                               \
      const int _sb = ((kt) + 3) & 3;                                           \
      gload16(gA + _gk,              &smem[_sb][0][wave * 512]);                \
      gload16(gA + halfStride + _gk, &smem[_sb][0][4096 + wave * 512]);         \
    }                                                                           \
    asm volatile("s_waitcnt vmcnt(" VMSTR ")" ::: "memory");                    \
    __builtin_amdgcn_s_barrier();                                               \
    asm volatile("" ::: "memory");                                              \
    bf16x8 _bf[4], _af[4];                                                      \
    _Pragma("unroll") for (int n = 0; n < 4; ++n)                               \
        _bf[n] = *(const bf16x8*)(_sB + boff + n * 512);                        \
    _Pragma("unroll") for (int m = 0; m < 4; ++m)                               \
        _af[m] = *(const bf16x8*)(_sA + aoff + m * 512);                        \
    __builtin_amdgcn_s_setprio(1);                                              \
    _Pragma("unroll") for (int m = 0; m < 4; ++m)                               \
      _Pragma("unroll") for (int n = 0; n < 4; ++n)                             \
        acc[m][n] = __builtin_amdgcn_mfma_f32_16x16x32_bf16(_af[m], _bf[n],     \
                                                            acc[m][n], 0, 0, 0);\
    __builtin_amdgcn_s_setprio(0);                                              \
    if (DO_STAGE) {                                                             \
      const size_t _gk = (size_t)((kt) + 3) * 32;                               \
      const int _sb = ((kt) + 3) & 3;                                           \
      gload16(gB + _gk,              &smem[_sb][1][wave * 512]);                \
      gload16(gB + halfStride + _gk, &smem[_sb][1][4096 + wave * 512]);         \
    }                                                                           \
    _Pragma("unroll") for (int m = 0; m < 4; ++m)                               \
        _af[m] = *(const bf16x8*)(_sA + aoff + 2048 + m * 512);                 \
    __builtin_amdgcn_s_setprio(1);                                              \
    _Pragma("unroll") for (int m = 0; m < 4; ++m)                               \
      _Pragma("unroll") for (int n = 0; n < 4; ++n)                             \
        acc[4 + m][n] = __builtin_amdgcn_mfma_f32_16x16x32_bf16(_af[m], _bf[n], \
                                                     acc[4 + m][n], 0, 0, 0);   \
    __builtin_amdgcn_s_setprio(0);                                              \
    asm volatile("" ::: "memory");                                              \
    __builtin_amdgcn_s_barrier();                                               \
    asm volatile("" ::: "memory");                                              \
  } while (0)

template<int BF16OUT>
__global__ __launch_bounds__(512, 2)
void gemm8p(const u16* __restrict__ A, const u16* __restrict__ B,
            const float* __restrict__ bias, void* __restrict__ Cv,
            int M, int Nn, int K)
{
    __shared__ __align__(128) u16 smem[4][2][8192];  // [ring buf][A|B][256 rows x 32 cols]

    const int tid  = threadIdx.x;
    const int lane = tid & 63;
    const int wave = tid >> 6;
    const int wm = wave >> 2;   // 0..1 -> row offset wm*128
    const int wn = wave & 3;    // 0..3 -> col offset wn*64

    // XCD-aware bijective swizzle (gridDim.x % 8 == 0 here)
    const int nbx = Nn >> 8;
    const int cpx = gridDim.x >> 3;
    const int bid = blockIdx.x;
    const int swz = (bid & 7) * cpx + (bid >> 3);
    const int bn = (swz % nbx) << 8;
    const int bm = (swz / nbx) << 8;

    // staging: thread t -> LDS row t/4 (of a 128-row half), 16B slot t%4;
    // source column pre-swizzled: slot_src = (t%4) ^ ((row>>1)&3)   (rule 21)
    const int srow = tid >> 2;
    const int scol = (((tid & 3) ^ ((srow >> 1) & 3)) << 3);
    const u16* gA = A + (size_t)(bm + srow) * K + scol;
    const u16* gB = B + (size_t)(bn + srow) * K + scol;
    const size_t halfStride = (size_t)128 * K;

    // frag ds_read offsets (elems): row*32 + (kslot ^ ((row>>1)&3))*8
    // frag rows = base(mult of 16) + fr, so (row>>1)&3 == (fr>>1)&3 == (lane>>1)&3
    const int fr = lane & 15;
    const int slotp = (((lane >> 4) ^ ((lane >> 1) & 3)) << 3);
    const int aoff = (wm * 128 + fr) * 32 + slotp;   // + m*512 per m-frag
    const int boff = (wn * 64  + fr) * 32 + slotp;   // + n*512 per n-frag

    f32x4 acc[8][4] = {};

    // prologue: stage tiles 0..2 (12 loads/thread outstanding)
    #pragma unroll
    for (int t = 0; t < 3; ++t) {
        const size_t gk = (size_t)t * 32;
        gload16(gA + gk,              &smem[t][0][wave * 512]);
        gload16(gA + halfStride + gk, &smem[t][0][4096 + wave * 512]);
        gload16(gB + gk,              &smem[t][1][wave * 512]);
        gload16(gB + halfStride + gk, &smem[t][1][4096 + wave * 512]);
    }

    const int NT = K >> 5;
    for (int k = 0; k <= NT - 4; ++k)
        VM_TILE(k, true, "10");
    VM_TILE(NT - 3, false, "8");
    VM_TILE(NT - 2, false, "4");
    VM_TILE(NT - 1, false, "0");

    // ---- coalesced epilogue through LDS (per-wave private slice) ----
    // C/D frag layout: col = lane&15, row = (lane>>4)*4 + j
    // scatter one 16x64 f32 chunk (stride 68 pad: write 2-way free, read
    // granule pos = (row+4cg+e)%8 uniform) then gather full rows.
    const int crow = (lane >> 4) << 2;
    const int ccol = lane & 15;
    float* lsw = (float*)&smem[0][0][0] + wave * 1152;   // 4608B per wave
    float bv[4];
    #pragma unroll
    for (int n = 0; n < 4; ++n) bv[n] = bias[bn + wn * 64 + n * 16 + ccol];

    const int erow = lane & 15;        // gather: lane -> row, col-group
    const int ecg  = lane >> 4;
    #pragma unroll
    for (int m = 0; m < 8; ++m) {
        #pragma unroll
        for (int n = 0; n < 4; ++n)
            #pragma unroll
            for (int j = 0; j < 4; ++j) {
                float v = acc[m][n][j] + bv[n];
                v = (v >= 0.f) ? v : 0.01f * v;
                lsw[(crow + j) * 68 + n * 16 + ccol] = v;
            }
        asm volatile("s_waitcnt lgkmcnt(0)" ::: "memory");
        const float* src = lsw + erow * 68 + ecg * 16;
        const size_t grow = (size_t)(bm + wm * 128 + m * 16 + erow);
        const int    gcol = bn + wn * 64 + ecg * 16;
        if (BF16OUT) {
            u16 tmp[16];
            #pragma unroll
            for (int e = 0; e < 16; ++e) tmp[e] = f2bf(src[e]);
            u16* dst = (u16*)Cv + grow * Nn + gcol;
            *(uint4*)dst       = ((const uint4*)tmp)[0];
            *(uint4*)(dst + 8) = ((const uint4*)tmp)[1];
        } else {
            float* dst = (float*)Cv + grow * Nn + gcol;
            #pragma unroll
            for (int e = 0; e < 4; ++e)
                ((float4*)dst)[e] = ((const float4*)src)[e];
        }
        asm volatile("" ::: "memory");   // keep m-chunks ordered (WAR on lsw)
    }
}

// ---------------- launch ----------------

extern "C" void kernel_launch(void* const* d_in, const int* in_sizes, int n_in,
                              void* d_out, int out_size, void* d_ws, size_t ws_size,
                              hipStream_t stream) {
    const float* x  = (const float*)d_in[0];
    const float* W0 = (const float*)d_in[1];
    const float* b0 = (const float*)d_in[2];
    const float* W1 = (const float*)d_in[3];
    const float* b1 = (const float*)d_in[4];
    const float* W2 = (const float*)d_in[5];
    const float* b2 = (const float*)d_in[6];

    const int N = 32768, D0 = 1024, D1 = 2048;

    char* ws = (char*)d_ws;
    u16* xbf = (u16*)ws;  ws += (size_t)N * D0 * 2;
    u16* h0  = (u16*)ws;  ws += (size_t)N * D1 * 2;
    u16* h1  = (u16*)ws;  ws += (size_t)N * D1 * 2;
    u16* w0q = (u16*)ws;  ws += (size_t)D1 * D0 * 2;
    u16* w1q = (u16*)ws;  ws += (size_t)D1 * D1 * 2;
    u16* w2q = (u16*)ws;  ws += (size_t)D1 * D1 * 2;
    unsigned int* scales = (unsigned int*)ws;

    zero3_k<<<1, 64, 0, stream>>>(scales);
    maxabs_k<<<256, 256, 0, stream>>>(W0, D1 * D0, scales + 0);
    maxabs_k<<<256, 256, 0, stream>>>(W1, D1 * D1, scales + 1);
    maxabs_k<<<256, 256, 0, stream>>>(W2, D1 * D1, scales + 2);
    quant_k<<<2048, 256, 0, stream>>>(W0, D1 * D0, scales + 0, 127.f, w0q);
    quant_k<<<2048, 256, 0, stream>>>(W1, D1 * D1, scales + 1, 7.f, w1q);
    quant_k<<<2048, 256, 0, stream>>>(W2, D1 * D1, scales + 2, 7.f, w2q);
    cvt_k<<<4096, 256, 0, stream>>>(x, xbf, (long)N * D0);

    const int blocks = (D1 / 256) * (N / 256);   // 8 * 128 = 1024, %8 == 0
    gemm8p<1><<<blocks, 512, 0, stream>>>(xbf, w0q, b0, h0, N, D1, D0);
    gemm8p<1><<<blocks, 512, 0, stream>>>(h0, w1q, b1, h1, N, D1, D1);
    gemm8p<0><<<blocks, 512, 0, stream>>>(h1, w2q, b2, d_out, N, D1, D1);
}